// Round 8
// baseline (27.360 us; speedup 1.0000x reference)
//
#include <hip/hip_runtime.h>
#include <math.h>

#define S 7
#define NB 2
#define NC 20
#define NOBJ 32
#define BATCH 16384
#define CELLS 49            // S*S
#define CH 30               // NB*5+NC
#define PRED_PER 1470       // CELLS*CH
#define LC_W 5.0f
#define LN_W 0.5f
#define WPB 4               // waves per block
#define IPW 4               // images per wave (sequential, prefetched)
#define IPB (WPB * IPW)     // 16 images per block
#define NBLK (BATCH / IPB)  // 1024
#define NWAVE (BATCH / IPW) // 4096 per-wave partials

__device__ __forceinline__ float iou_fn(float px, float py, float pw, float ph,
                                        float gx, float gy, float gw, float gh) {
    float px1 = px - pw * 0.5f, py1 = py - ph * 0.5f;
    float px2 = px + pw * 0.5f, py2 = py + ph * 0.5f;
    float gx1 = gx - gw * 0.5f, gy1 = gy - gh * 0.5f;
    float gx2 = gx + gw * 0.5f, gy2 = gy + gh * 0.5f;
    float iw = fmaxf(fminf(px2, gx2) - fmaxf(px1, gx1), 0.0f);
    float ih = fmaxf(fminf(py2, gy2) - fmaxf(py1, gy1), 0.0f);
    float inter = iw * ih;
    float uni = (px2 - px1) * (py2 - py1) + (gx2 - gx1) * (gy2 - gy1) - inter;
    return inter / (uni + 1e-6f);
}

__global__ __launch_bounds__(256, 4) void yolo_main(
    const float* __restrict__ pred, const float* __restrict__ tgt,
    float* __restrict__ partial)
{
    __shared__ unsigned long long cellkey[WPB][CELLS]; // wave-private winner keys
    __shared__ unsigned int      cmaskS[WPB][CELLS];   // wave-private class masks

    const int lane = threadIdx.x & 63;
    const int wv   = threadIdx.x >> 6;
    const int wid  = blockIdx.x * WPB + wv;
    const int b0   = wid * IPW;                        // first image of this wave

    const int cell = (lane < CELLS) ? lane : CELLS - 1;
    const int ol   = (lane < NOBJ) ? lane : NOBJ - 1;

    float accw = 0.0f;

    float4 qA[7]; float2 qtA; float tA[5];
    float4 qB[7]; float2 qtB; float tB[5];

    // ---- issue loads for one image (records strided per-lane, targets per-object) ----
    auto LOADI = [&](int b, float4 (&q)[7], float2& qt, float (&tt)[5]) {
        const float* crec = pred + (size_t)b * PRED_PER + cell * CH;
        const float4* cb4 = (const float4*)crec;
        #pragma unroll
        for (int k = 0; k < 7; ++k) q[k] = cb4[k];
        qt = ((const float2*)crec)[14];
        const float* tb = tgt + ((size_t)b * NOBJ + ol) * 5;
        #pragma unroll
        for (int k = 0; k < 5; ++k) tt[k] = tb[k];
    };

    // ---- full per-image pipeline (verified round-6/7 logic, barrier-free) ----
    auto COMPUTE = [&](int b, const float4 (&q)[7], const float2& qt, const float (&tt)[5]) {
        if (lane < CELLS) { cellkey[wv][lane] = 0ull; cmaskS[wv][lane] = 0u; }
        __builtin_amdgcn_wave_barrier();               // keep init before atomics

        float p[10];
        p[0] = q[0].x; p[1] = q[0].y; p[2] = q[0].z; p[3] = q[0].w;
        p[4] = q[1].x; p[5] = q[1].y; p[6] = q[1].z; p[7] = q[1].w;
        p[8] = q[2].x; p[9] = q[2].y;
        float s2a = q[2].z * q[2].z + q[2].w * q[2].w;
        float s2b = qt.x * qt.x + qt.y * qt.y;
        #pragma unroll
        for (int k = 3; k < 7; ++k) {
            s2a = fmaf(q[k].x, q[k].x, s2a);
            s2b = fmaf(q[k].y, q[k].y, s2b);
            s2a = fmaf(q[k].z, q[k].z, s2a);
            s2b = fmaf(q[k].w, q[k].w, s2b);
        }
        float sum2 = s2a + s2b;

        float cls = tt[0], cx = tt[1], cy = tt[2], tw = tt[3], th = tt[4];
        bool valid = (lane < NOBJ) && (cls >= 0.0f);
        int col = (int)floorf(cx * 7.0f); col = min(max(col, 0), 6);
        int row = (int)floorf(cy * 7.0f); row = min(max(row, 0), 6);
        int ocell = row * 7 + col;

        float c0 = __shfl(p[0], ocell), c1 = __shfl(p[1], ocell);
        float c2 = __shfl(p[2], ocell), c3 = __shfl(p[3], ocell);
        float c5 = __shfl(p[5], ocell), c6 = __shfl(p[6], ocell);
        float c7 = __shfl(p[7], ocell), c8 = __shfl(p[8], ocell);
        float iou0 = iou_fn(c0, c1, c2, c3, cx, cy, tw, th);
        float iou1 = iou_fn(c5, c6, c7, c8, cx, cy, tw, th);
        float bi = fmaxf(iou0, iou1);
        int   bj = (iou1 > iou0) ? 1 : 0;              // argmax, first index wins ties
        float bx = cx * 7.0f - (float)col;
        float by = cy * 7.0f - (float)row;
        if (valid) {
            unsigned long long key =
                ((unsigned long long)__float_as_uint(bi) << 32)
              | (unsigned long long)(0xffffffffu - (unsigned)lane);
            atomicMax(&cellkey[wv][ocell], key);       // segment_max + min-idx tiebreak
            atomicOr(&cmaskS[wv][ocell], 1u << (int)cls);
        }
        __builtin_amdgcn_wave_barrier();               // keep atomics before reads

        unsigned long long key = (lane < CELLS) ? cellkey[wv][lane] : 0ull;
        unsigned int m = (lane < CELLS) ? cmaskS[wv][lane] : 0u;
        bool obj = (key != 0ull);
        int  w_  = (int)(0xffffffffu - (unsigned)(key & 0xffffffffull));
        int  wsafe = obj ? w_ : 0;
        float biou = __uint_as_float((unsigned)(key >> 32));
        float gx  = __shfl(bx, wsafe);
        float gy  = __shfl(by, wsafe);
        float gw  = __shfl(tw, wsafe);
        float gh  = __shfl(th, wsafe);
        int   gbj = __shfl(bj, wsafe);

        float acc = 0.0f;
        if (lane < CELLS) {
            acc = LN_W * (p[4] * p[4] + p[9] * p[9]);  // noobj base: both confs
            if (obj) {
                float pcr = gbj ? p[9] : p[4];
                float dcf = pcr - biou;
                acc += dcf * dcf - LN_W * pcr * pcr;   // responsible conf correction
                acc += sum2 + (float)__popc(m);        // cls closed form
                float csum = 0.0f;
                unsigned int mm = m;
                const float* cbf = pred + (size_t)b * PRED_PER + cell * CH + 10;
                while (mm) {                           // ~1 bit typical, L1-hot
                    int k2 = __ffs(mm) - 1;
                    mm &= mm - 1u;
                    csum += cbf[k2];
                }
                acc -= 2.0f * csum;
                float px_ = gbj ? p[5] : p[0], py_ = gbj ? p[6] : p[1];
                float pw_ = gbj ? p[7] : p[2], ph_ = gbj ? p[8] : p[3];
                float dx = px_ - gx, dy = py_ - gy;
                float dw = sqrtf(fmaxf(pw_, 0.0f)) - sqrtf(gw);
                float dh = sqrtf(fmaxf(ph_, 0.0f)) - sqrtf(gh);
                acc += LC_W * (dx * dx + dy * dy + dw * dw + dh * dh);
            }
        }
        accw += acc;
    };

    // ---- static double-buffered pipeline over 4 images ----
    LOADI(b0 + 0, qA, qtA, tA);
    LOADI(b0 + 1, qB, qtB, tB);
    COMPUTE(b0 + 0, qA, qtA, tA);
    LOADI(b0 + 2, qA, qtA, tA);
    COMPUTE(b0 + 1, qB, qtB, tB);
    LOADI(b0 + 3, qB, qtB, tB);
    COMPUTE(b0 + 2, qA, qtA, tA);
    COMPUTE(b0 + 3, qB, qtB, tB);

    // ---- wave reduce, one partial per wave ----
    #pragma unroll
    for (int off = 32; off; off >>= 1) accw += __shfl_down(accw, off);
    if (lane == 0) partial[wid] = accw;
}

__global__ __launch_bounds__(256) void yolo_reduce(
    const float* __restrict__ partial, float* __restrict__ out)
{
    __shared__ float ws[4];
    const float4* p4 = (const float4*)partial;         // 1024 float4 = 4096 floats
    float acc = 0.0f;
    #pragma unroll
    for (int k = 0; k < 4; ++k) {
        float4 v = p4[threadIdx.x + k * 256];
        acc += v.x + v.y + v.z + v.w;
    }
    #pragma unroll
    for (int off = 32; off; off >>= 1) acc += __shfl_down(acc, off);
    if ((threadIdx.x & 63) == 0) ws[threadIdx.x >> 6] = acc;
    __syncthreads();
    if (threadIdx.x == 0)
        out[0] = (ws[0] + ws[1] + ws[2] + ws[3]) / (float)BATCH;
}

extern "C" void kernel_launch(void* const* d_in, const int* in_sizes, int n_in,
                              void* d_out, int out_size, void* d_ws, size_t ws_size,
                              hipStream_t stream) {
    const float* pred = (const float*)d_in[0];   // (BATCH, S, S, 30) fp32
    const float* tgt  = (const float*)d_in[1];   // (BATCH, NOBJ, 5) fp32
    float* out = (float*)d_out;
    float* partial = (float*)d_ws;               // NWAVE floats = 16 KB

    yolo_main<<<NBLK, 256, 0, stream>>>(pred, tgt, partial);
    yolo_reduce<<<1, 256, 0, stream>>>(partial, out);
}

// Round 10
// 25.699 us; speedup vs baseline: 1.0646x; 1.0646x over previous
//
#include <hip/hip_runtime.h>
#include <math.h>

#define S 7
#define NB 2
#define NC 20
#define NOBJ 32
#define BATCH 16384
#define CELLS 49            // S*S
#define CH 30               // NB*5+NC
#define PRED_PER 1470       // CELLS*CH
#define LC_W 5.0f
#define LN_W 0.5f
#define IPB 4               // images per block (one per wave, waves fully independent)
#define NBLK (BATCH / IPB)  // 4096

__device__ __forceinline__ float iou_fn(float px, float py, float pw, float ph,
                                        float gx, float gy, float gw, float gh) {
    float px1 = px - pw * 0.5f, py1 = py - ph * 0.5f;
    float px2 = px + pw * 0.5f, py2 = py + ph * 0.5f;
    float gx1 = gx - gw * 0.5f, gy1 = gy - gh * 0.5f;
    float gx2 = gx + gw * 0.5f, gy2 = gy + gh * 0.5f;
    float iw = fmaxf(fminf(px2, gx2) - fmaxf(px1, gx1), 0.0f);
    float ih = fmaxf(fminf(py2, gy2) - fmaxf(py1, gy1), 0.0f);
    float inter = iw * ih;
    float uni = (px2 - px1) * (py2 - py1) + (gx2 - gx1) * (gy2 - gy1) - inter;
    return inter / (uni + 1e-6f);
}

__global__ __launch_bounds__(256) void yolo_main(
    const float* __restrict__ pred, const float* __restrict__ tgt,
    float* __restrict__ partial)
{
    __shared__ unsigned long long cellkey[IPB][CELLS]; // wave-private winner keys
    __shared__ unsigned int      cmaskS[IPB][CELLS];   // wave-private class masks

    const int lane = threadIdx.x & 63;
    const int wv   = threadIdx.x >> 6;
    const int b    = blockIdx.x * IPB + wv;            // one image per wave

    if (lane < CELLS) { cellkey[wv][lane] = 0ull; cmaskS[wv][lane] = 0u; }
    __builtin_amdgcn_wave_barrier();                   // init before atomics (same wave)

    // ---- per-lane cell loads (lane = cell): 7x dwordx4 + 1x dwordx2 ----
    const int cell = (lane < CELLS) ? lane : CELLS - 1;
    const float* crec = pred + (size_t)b * PRED_PER + cell * CH;
    float4 q[7];
    const float4* cb4 = (const float4*)crec;
    #pragma unroll
    for (int k = 0; k < 7; ++k) q[k] = cb4[k];         // ch 0..27
    float2 qt = ((const float2*)crec)[14];             // ch 28,29

    // ---- per-lane target load (lane = object 0..31, masked) ----
    const int ol = (lane < NOBJ) ? lane : NOBJ - 1;
    const float* tb = tgt + ((size_t)b * NOBJ + ol) * 5;
    float cls = tb[0], cx = tb[1], cy = tb[2], tw = tb[3], th = tb[4];

    float p[10];                                       // ch 0..9 (two boxes)
    p[0] = q[0].x; p[1] = q[0].y; p[2] = q[0].z; p[3] = q[0].w;
    p[4] = q[1].x; p[5] = q[1].y; p[6] = q[1].z; p[7] = q[1].w;
    p[8] = q[2].x; p[9] = q[2].y;
    // sum of squares over the 20 class channels (ch 10..29)
    float s2a = q[2].z * q[2].z + q[2].w * q[2].w;
    float s2b = qt.x * qt.x + qt.y * qt.y;
    #pragma unroll
    for (int k = 3; k < 7; ++k) {
        s2a = fmaf(q[k].x, q[k].x, s2a);
        s2b = fmaf(q[k].y, q[k].y, s2b);
        s2a = fmaf(q[k].z, q[k].z, s2a);
        s2b = fmaf(q[k].w, q[k].w, s2b);
    }
    float sum2 = s2a + s2b;

    // ---- phase A: lane = object, masked ----
    bool valid = (lane < NOBJ) && (cls >= 0.0f);
    int col = (int)floorf(cx * 7.0f); col = min(max(col, 0), 6);
    int row = (int)floorf(cy * 7.0f); row = min(max(row, 0), 6);
    int ocell = row * 7 + col;

    // gather the cell's two boxes via cross-lane pull (no extra global reads)
    float c0 = __shfl(p[0], ocell), c1 = __shfl(p[1], ocell);
    float c2 = __shfl(p[2], ocell), c3 = __shfl(p[3], ocell);
    float c5 = __shfl(p[5], ocell), c6 = __shfl(p[6], ocell);
    float c7 = __shfl(p[7], ocell), c8 = __shfl(p[8], ocell);
    float iou0 = iou_fn(c0, c1, c2, c3, cx, cy, tw, th);
    float iou1 = iou_fn(c5, c6, c7, c8, cx, cy, tw, th);
    float bi = fmaxf(iou0, iou1);
    int   bj = (iou1 > iou0) ? 1 : 0;                  // argmax, first index wins ties
    float bx = cx * 7.0f - (float)col;
    float by = cy * 7.0f - (float)row;
    if (valid) {
        unsigned long long key =
            ((unsigned long long)__float_as_uint(bi) << 32)
          | (unsigned long long)(0xffffffffu - (unsigned)lane);
        atomicMax(&cellkey[wv][ocell], key);           // segment_max + min-idx tiebreak
        atomicOr(&cmaskS[wv][ocell], 1u << (int)cls);
    }
    __builtin_amdgcn_wave_barrier();                   // atomics before reads (same wave)

    // ---- phase C: lane = cell ----
    unsigned long long key = (lane < CELLS) ? cellkey[wv][lane] : 0ull;
    unsigned int m = (lane < CELLS) ? cmaskS[wv][lane] : 0u;
    bool obj = (key != 0ull);
    int  w_  = (int)(0xffffffffu - (unsigned)(key & 0xffffffffull));
    int  wsafe = obj ? w_ : 0;
    float biou = __uint_as_float((unsigned)(key >> 32));
    float gx  = __shfl(bx, wsafe);
    float gy  = __shfl(by, wsafe);
    float gw  = __shfl(tw, wsafe);
    float gh  = __shfl(th, wsafe);
    int   gbj = __shfl(bj, wsafe);

    float acc = 0.0f;
    if (lane < CELLS) {
        acc = LN_W * (p[4] * p[4] + p[9] * p[9]);      // noobj base: both confs
        if (obj) {
            // responsible-box conf correction: (p - biou)^2 replaces LN*p^2
            float pcr = gbj ? p[9] : p[4];
            float dcf = pcr - biou;
            acc += dcf * dcf - LN_W * pcr * pcr;
            // cls: sum (p-g)^2 = sum p^2 + popc(m) - 2 * sum_{k in m} p_k
            acc += sum2 + (float)__popc(m);
            float csum = 0.0f;
            unsigned int mm = m;
            const float* cbf = crec + 10;
            while (mm) {                                // ~1 bit typical, L1-hot loads
                int k2 = __ffs(mm) - 1;
                mm &= mm - 1u;
                csum += cbf[k2];
            }
            acc -= 2.0f * csum;
            // responsible box coords
            float px_ = gbj ? p[5] : p[0], py_ = gbj ? p[6] : p[1];
            float pw_ = gbj ? p[7] : p[2], ph_ = gbj ? p[8] : p[3];
            float dx = px_ - gx, dy = py_ - gy;
            float dw = sqrtf(fmaxf(pw_, 0.0f)) - sqrtf(gw);
            float dh = sqrtf(fmaxf(ph_, 0.0f)) - sqrtf(gh);
            acc += LC_W * (dx * dx + dy * dy + dw * dw + dh * dh);
        }
    }

    // ---- wave reduce, one partial per wave (= per image) ----
    #pragma unroll
    for (int off = 32; off; off >>= 1) acc += __shfl_down(acc, off);
    if (lane == 0) partial[b] = acc;
}

__global__ __launch_bounds__(256) void yolo_reduce(
    const float* __restrict__ partial, float* __restrict__ out)
{
    __shared__ float ws[4];
    const float4* p4 = (const float4*)partial;         // 4096 float4 = 16384 floats
    float acc = 0.0f;
    #pragma unroll
    for (int k = 0; k < 16; ++k) {                     // 256 thr x 16 = 4096 float4
        float4 v = p4[threadIdx.x + k * 256];
        acc += v.x + v.y + v.z + v.w;
    }
    #pragma unroll
    for (int off = 32; off; off >>= 1) acc += __shfl_down(acc, off);
    if ((threadIdx.x & 63) == 0) ws[threadIdx.x >> 6] = acc;
    __syncthreads();
    if (threadIdx.x == 0)
        out[0] = (ws[0] + ws[1] + ws[2] + ws[3]) / (float)BATCH;
}

extern "C" void kernel_launch(void* const* d_in, const int* in_sizes, int n_in,
                              void* d_out, int out_size, void* d_ws, size_t ws_size,
                              hipStream_t stream) {
    const float* pred = (const float*)d_in[0];   // (BATCH, S, S, 30) fp32
    const float* tgt  = (const float*)d_in[1];   // (BATCH, NOBJ, 5) fp32
    float* out = (float*)d_out;
    float* partial = (float*)d_ws;               // BATCH floats = 64 KB of per-image partials

    yolo_main<<<NBLK, 256, 0, stream>>>(pred, tgt, partial);
    yolo_reduce<<<1, 256, 0, stream>>>(partial, out);
}

// Round 11
// 25.160 us; speedup vs baseline: 1.0874x; 1.0214x over previous
//
#include <hip/hip_runtime.h>
#include <math.h>

#define S 7
#define NB 2
#define NC 20
#define NOBJ 32
#define BATCH 16384
#define CELLS 49            // S*S
#define CH 30               // NB*5+NC
#define PRED_PER 1470       // CELLS*CH
#define LC_W 5.0f
#define LN_W 0.5f
#define IPB 4               // images per block (one per wave)
#define NBLK (BATCH / IPB)  // 4096

__device__ __forceinline__ float iou_fn(float px, float py, float pw, float ph,
                                        float gx, float gy, float gw, float gh) {
    float px1 = px - pw * 0.5f, py1 = py - ph * 0.5f;
    float px2 = px + pw * 0.5f, py2 = py + ph * 0.5f;
    float gx1 = gx - gw * 0.5f, gy1 = gy - gh * 0.5f;
    float gx2 = gx + gw * 0.5f, gy2 = gy + gh * 0.5f;
    float iw = fmaxf(fminf(px2, gx2) - fmaxf(px1, gx1), 0.0f);
    float ih = fmaxf(fminf(py2, gy2) - fmaxf(py1, gy1), 0.0f);
    float inter = iw * ih;
    float uni = (px2 - px1) * (py2 - py1) + (gx2 - gx1) * (gy2 - gy1) - inter;
    return inter / (uni + 1e-6f);
}

__global__ __launch_bounds__(256) void yolo_main(
    const float* __restrict__ pred, const float* __restrict__ tgt,
    float* __restrict__ partial)
{
    __shared__ unsigned long long cellkey[IPB][CELLS]; // wave-private winner keys
    __shared__ unsigned int      cmaskS[IPB][CELLS];   // wave-private class masks
    __shared__ float             bsum[IPB];

    const int lane = threadIdx.x & 63;
    const int wv   = threadIdx.x >> 6;
    const int b    = blockIdx.x * IPB + wv;            // one image per wave

    if (lane < CELLS) { cellkey[wv][lane] = 0ull; cmaskS[wv][lane] = 0u; }
    __builtin_amdgcn_wave_barrier();                   // init before atomics (same wave)

    // ---- per-lane cell loads (lane = cell): 7x dwordx4 + 1x dwordx2 ----
    const int cell = (lane < CELLS) ? lane : CELLS - 1;
    const float* crec = pred + (size_t)b * PRED_PER + cell * CH;
    float4 q[7];
    const float4* cb4 = (const float4*)crec;
    #pragma unroll
    for (int k = 0; k < 7; ++k) q[k] = cb4[k];         // ch 0..27
    float2 qt = ((const float2*)crec)[14];             // ch 28,29

    // ---- per-lane target load (lane = object 0..31, masked) ----
    const int ol = (lane < NOBJ) ? lane : NOBJ - 1;
    const float* tb = tgt + ((size_t)b * NOBJ + ol) * 5;
    float cls = tb[0], cx = tb[1], cy = tb[2], tw = tb[3], th = tb[4];

    float p[10];                                       // ch 0..9 (two boxes)
    p[0] = q[0].x; p[1] = q[0].y; p[2] = q[0].z; p[3] = q[0].w;
    p[4] = q[1].x; p[5] = q[1].y; p[6] = q[1].z; p[7] = q[1].w;
    p[8] = q[2].x; p[9] = q[2].y;
    // sum of squares over the 20 class channels (ch 10..29)
    float s2a = q[2].z * q[2].z + q[2].w * q[2].w;
    float s2b = qt.x * qt.x + qt.y * qt.y;
    #pragma unroll
    for (int k = 3; k < 7; ++k) {
        s2a = fmaf(q[k].x, q[k].x, s2a);
        s2b = fmaf(q[k].y, q[k].y, s2b);
        s2a = fmaf(q[k].z, q[k].z, s2a);
        s2b = fmaf(q[k].w, q[k].w, s2b);
    }
    float sum2 = s2a + s2b;

    // ---- phase A: lane = object, masked ----
    bool valid = (lane < NOBJ) && (cls >= 0.0f);
    int col = (int)floorf(cx * 7.0f); col = min(max(col, 0), 6);
    int row = (int)floorf(cy * 7.0f); row = min(max(row, 0), 6);
    int ocell = row * 7 + col;

    // gather the cell's two boxes via cross-lane pull (no extra global reads)
    float c0 = __shfl(p[0], ocell), c1 = __shfl(p[1], ocell);
    float c2 = __shfl(p[2], ocell), c3 = __shfl(p[3], ocell);
    float c5 = __shfl(p[5], ocell), c6 = __shfl(p[6], ocell);
    float c7 = __shfl(p[7], ocell), c8 = __shfl(p[8], ocell);
    float iou0 = iou_fn(c0, c1, c2, c3, cx, cy, tw, th);
    float iou1 = iou_fn(c5, c6, c7, c8, cx, cy, tw, th);
    float bi = fmaxf(iou0, iou1);
    int   bj = (iou1 > iou0) ? 1 : 0;                  // argmax, first index wins ties
    float bx = cx * 7.0f - (float)col;
    float by = cy * 7.0f - (float)row;
    if (valid) {
        unsigned long long key =
            ((unsigned long long)__float_as_uint(bi) << 32)
          | (unsigned long long)(0xffffffffu - (unsigned)lane);
        atomicMax(&cellkey[wv][ocell], key);           // segment_max + min-idx tiebreak
        atomicOr(&cmaskS[wv][ocell], 1u << (int)cls);
    }
    __builtin_amdgcn_wave_barrier();                   // atomics before reads (same wave)

    // ---- phase C: lane = cell ----
    unsigned long long key = (lane < CELLS) ? cellkey[wv][lane] : 0ull;
    unsigned int m = (lane < CELLS) ? cmaskS[wv][lane] : 0u;
    bool obj = (key != 0ull);
    int  w_  = (int)(0xffffffffu - (unsigned)(key & 0xffffffffull));
    int  wsafe = obj ? w_ : 0;
    float biou = __uint_as_float((unsigned)(key >> 32));
    float gx  = __shfl(bx, wsafe);
    float gy  = __shfl(by, wsafe);
    float gw  = __shfl(tw, wsafe);
    float gh  = __shfl(th, wsafe);
    int   gbj = __shfl(bj, wsafe);

    float acc = 0.0f;
    if (lane < CELLS) {
        acc = LN_W * (p[4] * p[4] + p[9] * p[9]);      // noobj base: both confs
        if (obj) {
            // responsible-box conf correction: (p - biou)^2 replaces LN*p^2
            float pcr = gbj ? p[9] : p[4];
            float dcf = pcr - biou;
            acc += dcf * dcf - LN_W * pcr * pcr;
            // cls: sum (p-g)^2 = sum p^2 + popc(m) - 2 * sum_{k in m} p_k
            acc += sum2 + (float)__popc(m);
            float csum = 0.0f;
            unsigned int mm = m;
            const float* cbf = crec + 10;
            while (mm) {                                // ~1 bit typical, L1-hot loads
                int k2 = __ffs(mm) - 1;
                mm &= mm - 1u;
                csum += cbf[k2];
            }
            acc -= 2.0f * csum;
            // responsible box coords
            float px_ = gbj ? p[5] : p[0], py_ = gbj ? p[6] : p[1];
            float pw_ = gbj ? p[7] : p[2], ph_ = gbj ? p[8] : p[3];
            float dx = px_ - gx, dy = py_ - gy;
            float dw = sqrtf(fmaxf(pw_, 0.0f)) - sqrtf(gw);
            float dh = sqrtf(fmaxf(ph_, 0.0f)) - sqrtf(gh);
            acc += LC_W * (dx * dx + dy * dy + dw * dw + dh * dh);
        }
    }

    // ---- wave reduce -> cross-wave LDS sum -> one partial per block ----
    #pragma unroll
    for (int off = 32; off; off >>= 1) acc += __shfl_down(acc, off);
    if (lane == 0) bsum[wv] = acc;
    __syncthreads();
    if (threadIdx.x == 0)
        partial[blockIdx.x] = bsum[0] + bsum[1] + bsum[2] + bsum[3];
}

__global__ __launch_bounds__(256) void yolo_reduce(
    const float* __restrict__ partial, float* __restrict__ out)
{
    __shared__ float ws[4];
    const float4* p4 = (const float4*)partial;         // 1024 float4 = 4096 floats
    float acc = 0.0f;
    #pragma unroll
    for (int k = 0; k < 4; ++k) {
        float4 v = p4[threadIdx.x + k * 256];
        acc += v.x + v.y + v.z + v.w;
    }
    #pragma unroll
    for (int off = 32; off; off >>= 1) acc += __shfl_down(acc, off);
    if ((threadIdx.x & 63) == 0) ws[threadIdx.x >> 6] = acc;
    __syncthreads();
    if (threadIdx.x == 0)
        out[0] = (ws[0] + ws[1] + ws[2] + ws[3]) / (float)BATCH;
}

extern "C" void kernel_launch(void* const* d_in, const int* in_sizes, int n_in,
                              void* d_out, int out_size, void* d_ws, size_t ws_size,
                              hipStream_t stream) {
    const float* pred = (const float*)d_in[0];   // (BATCH, S, S, 30) fp32
    const float* tgt  = (const float*)d_in[1];   // (BATCH, NOBJ, 5) fp32
    float* out = (float*)d_out;
    float* partial = (float*)d_ws;               // NBLK floats = 16 KB

    yolo_main<<<NBLK, 256, 0, stream>>>(pred, tgt, partial);
    yolo_reduce<<<1, 256, 0, stream>>>(partial, out);
}

// Round 12
// 24.291 us; speedup vs baseline: 1.1263x; 1.0358x over previous
//
#include <hip/hip_runtime.h>
#include <math.h>

#define S 7
#define NB 2
#define NC 20
#define NOBJ 32
#define BATCH 16384
#define CELLS 49            // S*S
#define CH 30               // NB*5+NC
#define PRED_PER 1470       // CELLS*CH
#define TGT_PER (NOBJ * 5)  // 160
#define LC_W 5.0f
#define LN_W 0.5f
#define IPB 4               // images per block (one per wave)
#define NBLK (BATCH / IPB)  // 4096

__device__ __forceinline__ float iou_fn(float px, float py, float pw, float ph,
                                        float gx, float gy, float gw, float gh) {
    float px1 = px - pw * 0.5f, py1 = py - ph * 0.5f;
    float px2 = px + pw * 0.5f, py2 = py + ph * 0.5f;
    float gx1 = gx - gw * 0.5f, gy1 = gy - gh * 0.5f;
    float gx2 = gx + gw * 0.5f, gy2 = gy + gh * 0.5f;
    float iw = fmaxf(fminf(px2, gx2) - fmaxf(px1, gx1), 0.0f);
    float ih = fmaxf(fminf(py2, gy2) - fmaxf(py1, gy1), 0.0f);
    float inter = iw * ih;
    float uni = (px2 - px1) * (py2 - py1) + (gx2 - gx1) * (gy2 - gy1) - inter;
    return inter / (uni + 1e-6f);
}

__global__ __launch_bounds__(256) void yolo_main(
    const float* __restrict__ pred, const float* __restrict__ tgt,
    float* __restrict__ partial)
{
    __shared__ float st[IPB * TGT_PER];                // 2.5 KB staged targets
    __shared__ unsigned long long cellkey[IPB][CELLS]; // (iou_bits<<32)|(~obj_idx)
    __shared__ unsigned int      cmaskS[IPB][CELLS];   // multi-hot class bitmask
    __shared__ float             bsum[IPB];

    const int tid  = threadIdx.x;
    const int lane = tid & 63;
    const int wv   = tid >> 6;
    const int b    = blockIdx.x * IPB + wv;

    if (lane < CELLS) { cellkey[wv][lane] = 0ull; cmaskS[wv][lane] = 0u; }

    // ---- stage targets block-wide (coalesced float4, 16B-aligned) ----
    const float4* tg = (const float4*)(tgt + (size_t)blockIdx.x * (IPB * TGT_PER));
    if (tid < IPB * TGT_PER / 4) ((float4*)st)[tid] = tg[tid];

    // ---- per-lane cell loads (lane = cell), issued early ----
    const int cell = (lane < CELLS) ? lane : CELLS - 1;
    const float* ibase = pred + (size_t)b * PRED_PER;
    const float2* cb = (const float2*)(ibase + cell * CH);
    float2 pv[15];
    #pragma unroll
    for (int k = 0; k < 15; ++k) pv[k] = cb[k];

    float p[10];                                       // ch 0..9 (two boxes)
    #pragma unroll
    for (int k = 0; k < 5; ++k) { p[2*k] = pv[k].x; p[2*k+1] = pv[k].y; }
    // sum of squares over the 20 class channels (ch 10..29), two chains
    float s2a = 0.0f, s2b = 0.0f;
    #pragma unroll
    for (int k = 5; k < 15; ++k) {
        s2a = fmaf(pv[k].x, pv[k].x, s2a);
        s2b = fmaf(pv[k].y, pv[k].y, s2b);
    }
    float sum2 = s2a + s2b;
    __syncthreads();                                   // targets + table init visible

    // ---- phase A: lane = object (0..31), masked ----
    const int ol = (lane < NOBJ) ? lane : NOBJ - 1;
    const float* tb = st + wv * TGT_PER + ol * 5;
    float cls = tb[0], cx = tb[1], cy = tb[2], tw = tb[3], th = tb[4];
    bool valid = (lane < NOBJ) && (cls >= 0.0f);
    int col = (int)floorf(cx * 7.0f); col = min(max(col, 0), 6);
    int row = (int)floorf(cy * 7.0f); row = min(max(row, 0), 6);
    int ocell = row * 7 + col;

    // gather the cell's two boxes via cross-lane pull (no extra global reads)
    float c0 = __shfl(p[0], ocell), c1 = __shfl(p[1], ocell);
    float c2 = __shfl(p[2], ocell), c3 = __shfl(p[3], ocell);
    float c5 = __shfl(p[5], ocell), c6 = __shfl(p[6], ocell);
    float c7 = __shfl(p[7], ocell), c8 = __shfl(p[8], ocell);
    float iou0 = iou_fn(c0, c1, c2, c3, cx, cy, tw, th);
    float iou1 = iou_fn(c5, c6, c7, c8, cx, cy, tw, th);
    float bi = fmaxf(iou0, iou1);
    int   bj = (iou1 > iou0) ? 1 : 0;                  // argmax, first index wins ties
    float bx = cx * 7.0f - (float)col;
    float by = cy * 7.0f - (float)row;
    if (valid) {
        unsigned long long key =
            ((unsigned long long)__float_as_uint(bi) << 32)
          | (unsigned long long)(0xffffffffu - (unsigned)lane);
        atomicMax(&cellkey[wv][ocell], key);           // segment_max + min-index tiebreak
        atomicOr(&cmaskS[wv][ocell], 1u << (int)cls);
    }
    __syncthreads();

    // ---- phase C: lane = cell ----
    unsigned long long key = (lane < CELLS) ? cellkey[wv][lane] : 0ull;
    unsigned int m = (lane < CELLS) ? cmaskS[wv][lane] : 0u;
    bool obj = (key != 0ull);
    int  w_  = (int)(0xffffffffu - (unsigned)(key & 0xffffffffull));
    int  wsafe = obj ? w_ : 0;
    float biou = __uint_as_float((unsigned)(key >> 32));
    float gx  = __shfl(bx, wsafe);
    float gy  = __shfl(by, wsafe);
    float gw  = __shfl(tw, wsafe);
    float gh  = __shfl(th, wsafe);
    int   gbj = __shfl(bj, wsafe);

    float acc = 0.0f;
    if (lane < CELLS) {
        acc = LN_W * (p[4] * p[4] + p[9] * p[9]);      // noobj base: both confs
        if (obj) {
            // responsible-box conf correction: (p - biou)^2 replaces LN*p^2
            float pcr = gbj ? p[9] : p[4];
            float dcf = pcr - biou;
            acc += dcf * dcf - LN_W * pcr * pcr;
            // cls: sum (p-g)^2 = sum p^2 + popc(m) - 2 * sum_{k in m} p_k
            acc += sum2 + (float)__popc(m);
            float csum = 0.0f;
            unsigned int mm = m;
            const float* cbf = ibase + cell * CH + 10;
            while (mm) {                                // ~1 bit typical, L1-hot loads
                int k2 = __ffs(mm) - 1;
                mm &= mm - 1u;
                csum += cbf[k2];
            }
            acc -= 2.0f * csum;
            // responsible box coords
            float px_ = gbj ? p[5] : p[0], py_ = gbj ? p[6] : p[1];
            float pw_ = gbj ? p[7] : p[2], ph_ = gbj ? p[8] : p[3];
            float dx = px_ - gx, dy = py_ - gy;
            float dw = sqrtf(fmaxf(pw_, 0.0f)) - sqrtf(gw);
            float dh = sqrtf(fmaxf(ph_, 0.0f)) - sqrtf(gh);
            acc += LC_W * (dx * dx + dy * dy + dw * dw + dh * dh);
        }
    }

    #pragma unroll
    for (int off = 32; off; off >>= 1) acc += __shfl_down(acc, off);
    if (lane == 0) bsum[wv] = acc;
    __syncthreads();
    if (tid == 0) partial[blockIdx.x] = bsum[0] + bsum[1] + bsum[2] + bsum[3];
}

__global__ __launch_bounds__(256) void yolo_reduce(
    const float* __restrict__ partial, float* __restrict__ out)
{
    __shared__ float ws[4];
    const float4* p4 = (const float4*)partial;         // 1024 float4 = 4096 floats
    float acc = 0.0f;
    #pragma unroll
    for (int k = 0; k < 4; ++k) {
        float4 v = p4[threadIdx.x + k * 256];
        acc += v.x + v.y + v.z + v.w;
    }
    #pragma unroll
    for (int off = 32; off; off >>= 1) acc += __shfl_down(acc, off);
    if ((threadIdx.x & 63) == 0) ws[threadIdx.x >> 6] = acc;
    __syncthreads();
    if (threadIdx.x == 0)
        out[0] = (ws[0] + ws[1] + ws[2] + ws[3]) / (float)BATCH;
}

extern "C" void kernel_launch(void* const* d_in, const int* in_sizes, int n_in,
                              void* d_out, int out_size, void* d_ws, size_t ws_size,
                              hipStream_t stream) {
    const float* pred = (const float*)d_in[0];   // (BATCH, S, S, 30) fp32
    const float* tgt  = (const float*)d_in[1];   // (BATCH, NOBJ, 5) fp32
    float* out = (float*)d_out;
    float* partial = (float*)d_ws;               // NBLK floats = 16 KB

    yolo_main<<<NBLK, 256, 0, stream>>>(pred, tgt, partial);
    yolo_reduce<<<1, 256, 0, stream>>>(partial, out);
}